// Round 5
// baseline (481.479 us; speedup 1.0000x reference)
//
#include <hip/hip_runtime.h>

typedef unsigned short u16;
typedef unsigned int u32;
typedef __bf16 bf16x8 __attribute__((ext_vector_type(8)));
typedef __bf16 bf16x2 __attribute__((ext_vector_type(2)));
typedef float f32x4 __attribute__((ext_vector_type(4)));
typedef float f32x16 __attribute__((ext_vector_type(16)));

#define QSCALE 0.18033688011112f  // 0.125 * log2(e): folded into Q so p = 2^s

__device__ __forceinline__ u16 f2bf(float f) {
  u32 u = __builtin_bit_cast(u32, f);
  u += 0x7fffu + ((u >> 16) & 1u);   // RNE
  return (u16)(u >> 16);
}

// packed f32x2 -> bf16x2 (RNE), emits v_cvt_pk_bf16_f32 on gfx950
__device__ __forceinline__ u32 pkbf(float a, float b) {
  bf16x2 t = {(__bf16)a, (__bf16)b};
  return __builtin_bit_cast(u32, t);
}

__device__ __forceinline__ bf16x8 as_bf16x8(uint4 v) {
  return __builtin_bit_cast(bf16x8, v);
}

// async global->LDS, 16B per lane; LDS dest = wave-uniform base + lane*16
__device__ __forceinline__ void async16(const void* g, void* l) {
  __builtin_amdgcn_global_load_lds(
      (__attribute__((address_space(1))) void*)(g),
      (__attribute__((address_space(3))) void*)(l), 16, 0, 0);
}

// ---------------- merged prep: cast xq/xkv to bf16 + transpose-cast 3 weights
__global__ void prep_kernel(const float* __restrict__ xq, const float* __restrict__ xkv,
                            const float* __restrict__ Wq, const float* __restrict__ Wkv,
                            const float* __restrict__ Wo,
                            u16* __restrict__ Xq16, u16* __restrict__ Xkv16,
                            u16* __restrict__ WqT, u16* __restrict__ WkvT,
                            u16* __restrict__ WoT) {
  const int bid = blockIdx.x, tid = threadIdx.x;
  if (bid < 8192) {
    int i = bid * 256 + tid;
    const float* s; u16* d; int j;
    if (i < 1048576) { s = xq; d = Xq16; j = i; }
    else             { s = xkv; d = Xkv16; j = i - 1048576; }
    float4 v = ((const float4*)s)[j];
    ushort4 o;
    o.x = f2bf(v.x); o.y = f2bf(v.y); o.z = f2bf(v.z); o.w = f2bf(v.w);
    ((ushort4*)d)[j] = o;
    return;
  }
  const int b2 = bid - 8192;
  const int z = b2 >> 11, rem = b2 & 2047;
  const int by = rem >> 6, bx = rem & 63;
  const float* src; u16* dst; int Nd;
  if (z == 0)      { src = Wq;  dst = WqT;  Nd = 1024; }
  else if (z == 1) { src = Wkv; dst = WkvT; Nd = 2048; }
  else             { src = Wo;  dst = WoT;  Nd = 1024; }
  const int n0 = bx * 32, k0 = by * 32;
  if (n0 >= Nd) return;
  __shared__ float tile[32][33];
  const int tx = tid & 31, ty = tid >> 5;  // 32 x 8
#pragma unroll
  for (int j = 0; j < 4; ++j)
    tile[ty + 8 * j][tx] = src[(size_t)(k0 + ty + 8 * j) * Nd + n0 + tx];
  __syncthreads();
#pragma unroll
  for (int j = 0; j < 4; ++j)
    dst[(size_t)(n0 + ty + 8 * j) * 1024 + k0 + tx] = f2bf(tile[tx][ty + 8 * j]);
}

// ---------------------------------------------------------------- GEMM core
template <int MI>
static __device__ __forceinline__ void gemm_core(
    const u16* __restrict__ A, const u16* __restrict__ Bt, int m0,
    uint4* sA, uint4* sB, f32x4 (*acc)[4]) {
  const int tid = threadIdx.x;
  const int wv = tid >> 6, lane = tid & 63;
  const int quad = lane >> 4, l16 = lane & 15;
  const int wm = (wv >> 1) * (MI * 16), wn = (wv & 1) * 64;

  const int ib0 = wv * 128 + lane, ib1 = ib0 + 64;      // B: 512 slots
  const int br0 = ib0 >> 2, bc0 = (ib0 & 3) ^ ((br0 >> 1) & 3);
  const int br1 = ib1 >> 2, bc1 = (ib1 & 3) ^ ((br1 >> 1) & 3);
  const u16* gB0 = Bt + (size_t)br0 * 1024 + bc0 * 8;
  const u16* gB1 = Bt + (size_t)br1 * 1024 + bc1 * 8;

  const int ia0 = wv * (MI * 32) + lane;                // A: MI*128 slots
  const int ar0 = ia0 >> 2, ac0 = (ia0 & 3) ^ ((ar0 >> 1) & 3);
  const u16* gA0 = A + (size_t)(m0 + ar0) * 1024 + ac0 * 8;
  const int ia1 = ia0 + 64;
  const int ar1 = ia1 >> 2, ac1 = (ia1 & 3) ^ ((ar1 >> 1) & 3);
  const u16* gA1 = A + (size_t)(m0 + ar1) * 1024 + ac1 * 8;
  uint4* sAw = sA + wv * (MI * 32);
  uint4* sBw = sB + wv * 128;

  for (int k0 = 0; k0 < 1024; k0 += 32) {
    __syncthreads();
    async16(gA0 + k0, sAw);
    if (MI == 4) async16(gA1 + k0, sAw + 64);
    async16(gB0 + k0, sBw);
    async16(gB1 + k0, sBw + 64);
    __syncthreads();

    bf16x8 af[MI], bfr[4];
#pragma unroll
    for (int mi = 0; mi < MI; ++mi) {
      int r = wm + mi * 16 + l16;
      af[mi] = as_bf16x8(sA[r * 4 + (quad ^ ((r >> 1) & 3))]);
    }
#pragma unroll
    for (int ni = 0; ni < 4; ++ni) {
      int r = wn + ni * 16 + l16;
      bfr[ni] = as_bf16x8(sB[r * 4 + (quad ^ ((r >> 1) & 3))]);
    }
#pragma unroll
    for (int mi = 0; mi < MI; ++mi)
#pragma unroll
      for (int ni = 0; ni < 4; ++ni)
        acc[mi][ni] = __builtin_amdgcn_mfma_f32_16x16x32_bf16(
            af[mi], bfr[ni], acc[mi][ni], 0, 0, 0);
  }
}

// ------------------------------------- fused Q/K/V projection GEMM (N = 3072 virtual)
// Q, K -> plain [4096][1024] bf16 (coalesced); V -> [bh][dh][skv] packed ushort4.
__global__ __launch_bounds__(256, 3) void gemm_qkv(
    const u16* __restrict__ Xq, const u16* __restrict__ Xkv,
    const u16* __restrict__ WqT, const u16* __restrict__ WkvT,
    const float* __restrict__ bq, const float* __restrict__ bkv,
    u16* __restrict__ Qd, u16* __restrict__ Kd, u16* __restrict__ Vd) {
  __shared__ uint4 sA[512], sB[512];
  f32x4 acc[4][4] = {};
  const int n0 = blockIdx.x * 128, m0 = blockIdx.y * 128;
  const u16* A = (n0 < 1024) ? Xq : Xkv;
  const u16* Bt = (n0 < 1024) ? (WqT + (size_t)n0 * 1024)
                              : (WkvT + (size_t)(n0 - 1024) * 1024);
  const float* bias = (n0 < 1024) ? (bq + n0) : (bkv + (n0 - 1024));
  gemm_core<4>(A, Bt, m0, sA, sB, acc);

  const int tid = threadIdx.x, wv = tid >> 6, lane = tid & 63;
  const int quad = lane >> 4, l16 = lane & 15;
  const int wm = (wv >> 1) * 64, wn = (wv & 1) * 64;
  const int bb = m0 >> 11;
  const int gmb = m0 + wm + quad * 4;            // global row base (b*2048+ss)
  const int ssb = (m0 & 2047) + wm + quad * 4;   // seq base
#pragma unroll
  for (int ni = 0; ni < 4; ++ni) {
    const int gn = n0 + wn + ni * 16 + l16;      // virtual col; region uniform per ni
    const float bvn = bias[wn + ni * 16 + l16];
    if (gn < 1024) {                             // Q plain, pre-scaled
      u16* base = Qd + gn;
#pragma unroll
      for (int mi = 0; mi < 4; ++mi)
#pragma unroll
        for (int r = 0; r < 4; ++r)
          base[(size_t)(gmb + mi * 16 + r) * 1024] = f2bf((acc[mi][ni][r] + bvn) * QSCALE);
    } else if (gn < 2048) {                      // K plain
      u16* base = Kd + (gn - 1024);
#pragma unroll
      for (int mi = 0; mi < 4; ++mi)
#pragma unroll
        for (int r = 0; r < 4; ++r)
          base[(size_t)(gmb + mi * 16 + r) * 1024] = f2bf(acc[mi][ni][r] + bvn);
    } else {                                     // V^T: [bh][dh][skv], packed x4
      const int col = gn - 2048, hh = col >> 6, dh = col & 63;
      u16* base = Vd + ((size_t)(bb * 16 + hh) * 64 + dh) * 2048 + ssb;
#pragma unroll
      for (int mi = 0; mi < 4; ++mi) {
        ushort4 o;
        o.x = f2bf(acc[mi][ni][0] + bvn);
        o.y = f2bf(acc[mi][ni][1] + bvn);
        o.z = f2bf(acc[mi][ni][2] + bvn);
        o.w = f2bf(acc[mi][ni][3] + bvn);
        *(ushort4*)(base + mi * 16) = o;
      }
    }
  }
}

// ---------------------------------------------------------------- flash attention
// R8 = R7 per-wave structure + 4-way kv-split (R7 post-mortem: TLP responded
// ~linearly, 1->2 waves/SIMD gave -22%; counters still ~50% issue-idle, so push
// to 4/SIMD). 1024 thr = 16 waves: grp = wv>>2 owns kv tiles {grp, 4+grp, ...}
// (8 tiles each), wq = wv&3 owns 64 q-rows (BQ=256, grid 256 = 1 block/CU,
// 16 waves/CU = 4/SIMD). Each grp has its own K/V double-buffer in a 128 KB
// shared pool; 8 main-loop barriers, prefetch distance 4 tiles. Per-tile LDS
// traffic per unit work unchanged vs R7 (the R5 wall stays fixed). Epilogue:
// 4-partial O merge reuses the 128 KB pool as f32 scratch in two rounds
// (grps 1+2 = 128 KB exactly, then grp 3), grp 0 accumulates + normalizes +
// stores. T5 setprio around MFMA clusters (4 waves/SIMD at skewed phases now
// give the CU scheduler something to arbitrate). launch_bounds(1024,4) caps
// VGPR at 128 (R7 measured 124 with the identical main-loop live set).
__global__ __launch_bounds__(1024, 4) void flash_attn(
    const u16* __restrict__ Q, const u16* __restrict__ K,
    const u16* __restrict__ V, u16* __restrict__ O) {
  __shared__ uint4 sbuf[8192];              // 128 KB: [g*1024 + d*512] K, +4096 V
  __shared__ float sLB[4][256];             // lsum partials per grp
  __shared__ float sLA[256];                // 1/ltot transpose (grp-0 private)

  const int tid = threadIdx.x;
  const int wv = tid >> 6, lane = tid & 63;
  const int grp = wv >> 2, wq = wv & 3;     // kv-group, q-subblock owner
  const int c = lane & 31, hh = lane >> 5;  // col-in-block, half
  const int hb = blockIdx.x & 31;           // fast dim: (h, b) -> fixes XCD
  const int q0 = (blockIdx.x >> 5) * 256;   // slow dim: q-block
  const int h = hb & 15, bz = hb >> 4;

  // Q,K plain [B*S][1024]; V^T [bh][dh][skv]. grp offset = 64 kv rows/cols.
  const u16* Qb = Q + ((size_t)(bz * 2048 + q0 + wq * 64)) * 1024 + h * 64;
  const u16* Kb = K + ((size_t)(bz * 2048 + grp * 64)) * 1024 + h * 64;
  const u16* Vb = V + ((size_t)(bz * 16 + h)) * 64 * 2048 + grp * 64;

  uint4* sKg = sbuf + grp * 1024;           // this group's K dbuf (2 x 512)
  uint4* sVg = sbuf + 4096 + grp * 1024;    // this group's V dbuf (2 x 512)

  // staging: slot i -> row i>>3, LDS chunk i&7 holds global chunk (i&7)^(row&7)
  const int i0 = wq * 128 + lane, i1 = i0 + 64;
  const int r0 = i0 >> 3, r1 = i1 >> 3;
  const int ck0 = (i0 & 7) ^ (r0 & 7), ck1 = (i1 & 7) ^ (r1 & 7);
  const u16* gK0 = Kb + (size_t)r0 * 1024 + ck0 * 8;
  const u16* gK1 = Kb + (size_t)r1 * 1024 + ck1 * 8;
  const u16* gV0 = Vb + (size_t)r0 * 2048 + ck0 * 8;
  const u16* gV1 = Vb + (size_t)r1 * 2048 + ck1 * 8;
  const int wo = wq * 128;

  // Q B-frags [g][s]: B[n=q][k=d], n = c, k = hh*8 + 16s + j
  bf16x8 qf[2][4];
#pragma unroll
  for (int g = 0; g < 2; ++g) {
    const u16* qr = Qb + (size_t)(32 * g + c) * 1024 + hh * 8;
#pragma unroll
    for (int s = 0; s < 4; ++s)
      qf[g][s] = as_bf16x8(*(const uint4*)(qr + 16 * s));
  }

  f32x16 oacc[2][2] = {};                   // [g][nb]: O[32g+qr][32nb+c]
  float lp[2] = {0.f, 0.f};                 // lsum partial per g (this half)

  // prologue: this group's tile 0 (global tile = grp) -> dbuf 0
  async16(gK0, sKg + wo);
  async16(gK1, sKg + wo + 64);
  async16(gV0, sVg + wo);
  async16(gV1, sVg + wo + 64);

  for (int t = 0; t < 8; ++t) {             // my tile = 4t + grp
    const int cur = t & 1;
    __syncthreads();   // drains my staging issued one iter ago
    if (t < 7) {
      const size_t ko = (size_t)(t + 1) * 256 * 1024;  // +4 tiles = 256 K rows
      const int vo = (t + 1) * 256;                    // 256 kv cols
      async16(gK0 + ko, sKg + (cur ^ 1) * 512 + wo);
      async16(gK1 + ko, sKg + (cur ^ 1) * 512 + wo + 64);
      async16(gV0 + vo, sVg + (cur ^ 1) * 512 + wo);
      async16(gV1 + vo, sVg + (cur ^ 1) * 512 + wo + 64);
    }
    const uint4* K_ = sKg + cur * 512;
    const uint4* V_ = sVg + cur * 512;

    // K A-frags [b][s]: A[m=kv=32b+c][k=d], chunk (2s+hh)^(row&7)
    // V B-frags [nb][ks]: B[k=kv][n=dh=32nb+c], chunk (2ks+hh)^(row&7)
    bf16x8 kf[2][4], vf[2][4];
#pragma unroll
    for (int b = 0; b < 2; ++b) {
      const int row = 32 * b + c, sw = row & 7;
#pragma unroll
      for (int s = 0; s < 4; ++s) {
        kf[b][s] = as_bf16x8(K_[row * 8 + ((2 * s + hh) ^ sw)]);
        vf[b][s] = as_bf16x8(V_[row * 8 + ((2 * s + hh) ^ sw)]);
      }
    }

    // S^T per (b,g) -> exp2 -> in-register pack to PV A-frags pa[g][2b+sig]
    bf16x8 pa[2][4];
#pragma unroll
    for (int b = 0; b < 2; ++b)
#pragma unroll
      for (int g = 0; g < 2; ++g) {
        f32x16 sAcc = {};
        __builtin_amdgcn_s_setprio(1);
#pragma unroll
        for (int s = 0; s < 4; ++s)
          sAcc = __builtin_amdgcn_mfma_f32_32x32x16_bf16(kf[b][s], qf[g][s], sAcc, 0, 0, 0);
        __builtin_amdgcn_s_setprio(0);
        // lane holds S[q=c][kv32 = (r&3)+8*(r>>2)+4*hh] for this 32-kv block
        float e[16];
#pragma unroll
        for (int r = 0; r < 16; ++r) e[r] = __builtin_amdgcn_exp2f(sAcc[r]);
        float t0 = (e[0] + e[1]) + (e[2] + e[3]);
        float t1 = (e[4] + e[5]) + (e[6] + e[7]);
        float t2 = (e[8] + e[9]) + (e[10] + e[11]);
        float t3 = (e[12] + e[13]) + (e[14] + e[15]);
        lp[g] += (t0 + t1) + (t2 + t3);
        // pack pairs (kv even, odd) then cross-half swap: frag sig=0 covers
        // kv 0..15 of this block (k = 8*hh + j), sig=1 covers kv 16..31.
        u32 wA0 = pkbf(e[0], e[1]),   wA1 = pkbf(e[2], e[3]);
        u32 wB0 = pkbf(e[4], e[5]),   wB1 = pkbf(e[6], e[7]);
        u32 wC0 = pkbf(e[8], e[9]),   wC1 = pkbf(e[10], e[11]);
        u32 wD0 = pkbf(e[12], e[13]), wD1 = pkbf(e[14], e[15]);
        asm("v_permlane32_swap_b32 %0, %1" : "+v"(wA0), "+v"(wB0));
        asm("v_permlane32_swap_b32 %0, %1" : "+v"(wA1), "+v"(wB1));
        asm("v_permlane32_swap_b32 %0, %1" : "+v"(wC0), "+v"(wD0));
        asm("v_permlane32_swap_b32 %0, %1" : "+v"(wC1), "+v"(wD1));
        uint4 f0 = {wA0, wA1, wB0, wB1};
        uint4 f1 = {wC0, wC1, wD0, wD1};
        pa[g][2 * b]     = as_bf16x8(f0);
        pa[g][2 * b + 1] = as_bf16x8(f1);
      }

    // PV: O[q][dh] += P * V
    __builtin_amdgcn_s_setprio(1);
#pragma unroll
    for (int g = 0; g < 2; ++g)
#pragma unroll
      for (int nb = 0; nb < 2; ++nb)
#pragma unroll
        for (int ks = 0; ks < 4; ++ks)
          oacc[g][nb] = __builtin_amdgcn_mfma_f32_32x32x16_bf16(
              pa[g][ks], vf[nb][ks], oacc[g][nb], 0, 0, 0);
    __builtin_amdgcn_s_setprio(0);
  }

  // lsum: combine the two 32-kv halves within this wave; publish per-grp
  float rtot[2];
#pragma unroll
  for (int g = 0; g < 2; ++g) {
    u32 a = __builtin_bit_cast(u32, lp[g]);
    u32 b = a;
    asm("v_permlane32_swap_b32 %0, %1" : "+v"(a), "+v"(b));
    rtot[g] = __builtin_bit_cast(float, a) + __builtin_bit_cast(float, b);
    sLB[grp][wq * 64 + 32 * g + c] = rtot[g];   // both halves write same value
  }

  __syncthreads();   // (A) last-tile reads done -> sbuf reusable; sLB visible
  float* scr = (float*)sbuf;                // 32768 f32 scratch

  // round 1: grps 1,2 publish partial O (2 x 64 KB = full pool)
  if (grp == 1 || grp == 2) {
#pragma unroll
    for (int g = 0; g < 2; ++g)
#pragma unroll
      for (int nb = 0; nb < 2; ++nb) {
        float* dst = scr + ((((grp - 1) * 4 + wq) * 4) + g * 2 + nb) * 1024;
#pragma unroll
        for (int r = 0; r < 16; ++r)
          dst[r * 64 + lane] = oacc[g][nb][r];
      }
  }
  __syncthreads();   // (B)
  if (grp == 0) {
#pragma unroll
    for (int src = 0; src < 2; ++src)
#pragma unroll
      for (int g = 0; g < 2; ++g)
#pragma unroll
        for (int nb = 0; nb < 2; ++nb) {
          const float* sp = scr + (((src * 4 + wq) * 4) + g * 2 + nb) * 1024;
#pragma unroll
          for (int r = 0; r < 16; ++r)
            oacc[g][nb][r] += sp[r * 64 + lane];
        }
  }
  __syncthreads();   // (C)
  // round 2: grp 3 publishes (64 KB)
  if (grp == 3) {
#pragma unroll
    for (int g = 0; g < 2; ++g)
#pragma unroll
      for (int nb = 0; nb < 2; ++nb) {
        float* dst = scr + ((wq * 4) + g * 2 + nb) * 1024;
#pragma unroll
        for (int r = 0; r < 16; ++r)
          dst[r * 64 + lane] = oacc[g][nb][r];
      }
  }
  __syncthreads();   // (D)
  if (grp == 0) {
#pragma unroll
    for (int g = 0; g < 2; ++g) {
#pragma unroll
      for (int nb = 0; nb < 2; ++nb) {
        const float* sp = scr + ((wq * 4) + g * 2 + nb) * 1024;
#pragma unroll
        for (int r = 0; r < 16; ++r)
          oacc[g][nb][r] += sp[r * 64 + lane];
      }
      const int li = wq * 64 + 32 * g + c;
      float tot = rtot[g] + sLB[1][li] + sLB[2][li] + sLB[3][li];
      sLA[li] = 1.0f / tot;
    }
    // epilogue: O16 plain [4096][1024] bf16, normalized
#pragma unroll
    for (int g = 0; g < 2; ++g) {
      u16* Ob = O + ((size_t)(bz * 2048 + q0 + wq * 64 + 32 * g)) * 1024 + h * 64;
#pragma unroll
      for (int nb = 0; nb < 2; ++nb)
#pragma unroll
        for (int r = 0; r < 16; ++r) {
          const int qr = (r & 3) + 8 * (r >> 2) + 4 * hh;
          float rl = sLA[wq * 64 + 32 * g + qr];   // broadcast read
          Ob[(size_t)qr * 1024 + nb * 32 + c] = f2bf(oacc[g][nb][r] * rl);
        }
    }
  }
}

// ---------------------------------------------------------------- output projection
__global__ __launch_bounds__(256, 2) void gemm_out(
    const u16* __restrict__ A, const u16* __restrict__ Bt,
    const float* __restrict__ bias, float* __restrict__ C) {
  __shared__ uint4 sA[256], sB[512];
  f32x4 acc[2][4] = {};
  const int n0 = blockIdx.x * 128, m0 = blockIdx.y * 64;
  gemm_core<2>(A, Bt + (size_t)n0 * 1024, m0, sA, sB, acc);

  const int tid = threadIdx.x, wv = tid >> 6, lane = tid & 63;
  const int quad = lane >> 4, l16 = lane & 15;
  const int wm = (wv >> 1) * 32, wn = (wv & 1) * 64;
  float bv[4];
#pragma unroll
  for (int ni = 0; ni < 4; ++ni) bv[ni] = bias[n0 + wn + ni * 16 + l16];
#pragma unroll
  for (int mi = 0; mi < 2; ++mi)
#pragma unroll
    for (int ni = 0; ni < 4; ++ni)
#pragma unroll
      for (int r = 0; r < 4; ++r) {
        int gm = m0 + wm + mi * 16 + quad * 4 + r;
        int gn = n0 + wn + ni * 16 + l16;
        C[(size_t)gm * 1024 + gn] = acc[mi][ni][r] + bv[ni];
      }
}

extern "C" void kernel_launch(void* const* d_in, const int* in_sizes, int n_in,
                              void* d_out, int out_size, void* d_ws, size_t ws_size,
                              hipStream_t stream) {
  const float* xq  = (const float*)d_in[0];
  const float* xkv = (const float*)d_in[1];
  const float* Wq  = (const float*)d_in[2];
  const float* bq  = (const float*)d_in[3];
  const float* Wkv = (const float*)d_in[4];
  const float* bkv = (const float*)d_in[5];
  const float* Wo  = (const float*)d_in[6];
  const float* bo  = (const float*)d_in[7];
  float* out = (float*)d_out;

  char* p = (char*)d_ws;                       // 56 MiB total
  u16* Xq16  = (u16*)p; p += (size_t)8 << 20;  // [4096][1024] bf16
  u16* Xkv16 = (u16*)p; p += (size_t)8 << 20;
  u16* WqT   = (u16*)p; p += (size_t)2 << 20;  // [1024][1024]
  u16* WkvT  = (u16*)p; p += (size_t)4 << 20;  // [2048][1024]
  u16* WoT   = (u16*)p; p += (size_t)2 << 20;
  u16* Q16   = (u16*)p; p += (size_t)8 << 20;  // plain [4096][1024], pre-scaled
  u16* K16   = (u16*)p; p += (size_t)8 << 20;  // plain [4096][1024]
  u16* Vt16  = (u16*)p; p += (size_t)8 << 20;  // [bh][dh][skv]
  u16* O16   = (u16*)p; p += (size_t)8 << 20;  // plain [4096][1024]

  prep_kernel<<<14336, 256, 0, stream>>>(xq, xkv, Wq, Wkv, Wo,
                                         Xq16, Xkv16, WqT, WkvT, WoT);
  gemm_qkv<<<dim3(24, 32), 256, 0, stream>>>(Xq16, Xkv16, WqT, WkvT, bq, bkv,
                                             Q16, K16, Vt16);
  flash_attn<<<256, 1024, 0, stream>>>(Q16, K16, Vt16, O16);
  gemm_out<<<dim3(8, 64), 256, 0, stream>>>(O16, WoT, bo, out);
}

// Round 6
// 196.443 us; speedup vs baseline: 2.4510x; 2.4510x over previous
//
#include <hip/hip_runtime.h>

typedef unsigned short u16;
typedef unsigned int u32;
typedef __bf16 bf16x8 __attribute__((ext_vector_type(8)));
typedef __bf16 bf16x2 __attribute__((ext_vector_type(2)));
typedef float f32x4 __attribute__((ext_vector_type(4)));
typedef float f32x16 __attribute__((ext_vector_type(16)));

#define QSCALE 0.18033688011112f  // 0.125 * log2(e): folded into Q so p = 2^s

__device__ __forceinline__ u16 f2bf(float f) {
  u32 u = __builtin_bit_cast(u32, f);
  u += 0x7fffu + ((u >> 16) & 1u);   // RNE
  return (u16)(u >> 16);
}

// packed f32x2 -> bf16x2 (RNE), emits v_cvt_pk_bf16_f32 on gfx950
__device__ __forceinline__ u32 pkbf(float a, float b) {
  bf16x2 t = {(__bf16)a, (__bf16)b};
  return __builtin_bit_cast(u32, t);
}

__device__ __forceinline__ bf16x8 as_bf16x8(uint4 v) {
  return __builtin_bit_cast(bf16x8, v);
}

// async global->LDS, 16B per lane; LDS dest = wave-uniform base + lane*16
__device__ __forceinline__ void async16(const void* g, void* l) {
  __builtin_amdgcn_global_load_lds(
      (__attribute__((address_space(1))) void*)(g),
      (__attribute__((address_space(3))) void*)(l), 16, 0, 0);
}

// ---------------- merged prep: cast xq/xkv to bf16 + transpose-cast 3 weights
__global__ void prep_kernel(const float* __restrict__ xq, const float* __restrict__ xkv,
                            const float* __restrict__ Wq, const float* __restrict__ Wkv,
                            const float* __restrict__ Wo,
                            u16* __restrict__ Xq16, u16* __restrict__ Xkv16,
                            u16* __restrict__ WqT, u16* __restrict__ WkvT,
                            u16* __restrict__ WoT) {
  const int bid = blockIdx.x, tid = threadIdx.x;
  if (bid < 8192) {
    int i = bid * 256 + tid;
    const float* s; u16* d; int j;
    if (i < 1048576) { s = xq; d = Xq16; j = i; }
    else             { s = xkv; d = Xkv16; j = i - 1048576; }
    float4 v = ((const float4*)s)[j];
    ushort4 o;
    o.x = f2bf(v.x); o.y = f2bf(v.y); o.z = f2bf(v.z); o.w = f2bf(v.w);
    ((ushort4*)d)[j] = o;
    return;
  }
  const int b2 = bid - 8192;
  const int z = b2 >> 11, rem = b2 & 2047;
  const int by = rem >> 6, bx = rem & 63;
  const float* src; u16* dst; int Nd;
  if (z == 0)      { src = Wq;  dst = WqT;  Nd = 1024; }
  else if (z == 1) { src = Wkv; dst = WkvT; Nd = 2048; }
  else             { src = Wo;  dst = WoT;  Nd = 1024; }
  const int n0 = bx * 32, k0 = by * 32;
  if (n0 >= Nd) return;
  __shared__ float tile[32][33];
  const int tx = tid & 31, ty = tid >> 5;  // 32 x 8
#pragma unroll
  for (int j = 0; j < 4; ++j)
    tile[ty + 8 * j][tx] = src[(size_t)(k0 + ty + 8 * j) * Nd + n0 + tx];
  __syncthreads();
#pragma unroll
  for (int j = 0; j < 4; ++j)
    dst[(size_t)(n0 + ty + 8 * j) * 1024 + k0 + tx] = f2bf(tile[tx][ty + 8 * j]);
}

// ---------------------------------------------------------------- GEMM core
template <int MI>
static __device__ __forceinline__ void gemm_core(
    const u16* __restrict__ A, const u16* __restrict__ Bt, int m0,
    uint4* sA, uint4* sB, f32x4 (*acc)[4]) {
  const int tid = threadIdx.x;
  const int wv = tid >> 6, lane = tid & 63;
  const int quad = lane >> 4, l16 = lane & 15;
  const int wm = (wv >> 1) * (MI * 16), wn = (wv & 1) * 64;

  const int ib0 = wv * 128 + lane, ib1 = ib0 + 64;      // B: 512 slots
  const int br0 = ib0 >> 2, bc0 = (ib0 & 3) ^ ((br0 >> 1) & 3);
  const int br1 = ib1 >> 2, bc1 = (ib1 & 3) ^ ((br1 >> 1) & 3);
  const u16* gB0 = Bt + (size_t)br0 * 1024 + bc0 * 8;
  const u16* gB1 = Bt + (size_t)br1 * 1024 + bc1 * 8;

  const int ia0 = wv * (MI * 32) + lane;                // A: MI*128 slots
  const int ar0 = ia0 >> 2, ac0 = (ia0 & 3) ^ ((ar0 >> 1) & 3);
  const u16* gA0 = A + (size_t)(m0 + ar0) * 1024 + ac0 * 8;
  const int ia1 = ia0 + 64;
  const int ar1 = ia1 >> 2, ac1 = (ia1 & 3) ^ ((ar1 >> 1) & 3);
  const u16* gA1 = A + (size_t)(m0 + ar1) * 1024 + ac1 * 8;
  uint4* sAw = sA + wv * (MI * 32);
  uint4* sBw = sB + wv * 128;

  for (int k0 = 0; k0 < 1024; k0 += 32) {
    __syncthreads();
    async16(gA0 + k0, sAw);
    if (MI == 4) async16(gA1 + k0, sAw + 64);
    async16(gB0 + k0, sBw);
    async16(gB1 + k0, sBw + 64);
    __syncthreads();

    bf16x8 af[MI], bfr[4];
#pragma unroll
    for (int mi = 0; mi < MI; ++mi) {
      int r = wm + mi * 16 + l16;
      af[mi] = as_bf16x8(sA[r * 4 + (quad ^ ((r >> 1) & 3))]);
    }
#pragma unroll
    for (int ni = 0; ni < 4; ++ni) {
      int r = wn + ni * 16 + l16;
      bfr[ni] = as_bf16x8(sB[r * 4 + (quad ^ ((r >> 1) & 3))]);
    }
#pragma unroll
    for (int mi = 0; mi < MI; ++mi)
#pragma unroll
      for (int ni = 0; ni < 4; ++ni)
        acc[mi][ni] = __builtin_amdgcn_mfma_f32_16x16x32_bf16(
            af[mi], bfr[ni], acc[mi][ni], 0, 0, 0);
  }
}

// ------------------------------------- fused Q/K/V projection GEMM (N = 3072 virtual)
// Q, K -> plain [4096][1024] bf16 (coalesced); V -> [bh][dh][skv] packed ushort4.
__global__ __launch_bounds__(256, 3) void gemm_qkv(
    const u16* __restrict__ Xq, const u16* __restrict__ Xkv,
    const u16* __restrict__ WqT, const u16* __restrict__ WkvT,
    const float* __restrict__ bq, const float* __restrict__ bkv,
    u16* __restrict__ Qd, u16* __restrict__ Kd, u16* __restrict__ Vd) {
  __shared__ uint4 sA[512], sB[512];
  f32x4 acc[4][4] = {};
  const int n0 = blockIdx.x * 128, m0 = blockIdx.y * 128;
  const u16* A = (n0 < 1024) ? Xq : Xkv;
  const u16* Bt = (n0 < 1024) ? (WqT + (size_t)n0 * 1024)
                              : (WkvT + (size_t)(n0 - 1024) * 1024);
  const float* bias = (n0 < 1024) ? (bq + n0) : (bkv + (n0 - 1024));
  gemm_core<4>(A, Bt, m0, sA, sB, acc);

  const int tid = threadIdx.x, wv = tid >> 6, lane = tid & 63;
  const int quad = lane >> 4, l16 = lane & 15;
  const int wm = (wv >> 1) * 64, wn = (wv & 1) * 64;
  const int bb = m0 >> 11;
  const int gmb = m0 + wm + quad * 4;            // global row base (b*2048+ss)
  const int ssb = (m0 & 2047) + wm + quad * 4;   // seq base
#pragma unroll
  for (int ni = 0; ni < 4; ++ni) {
    const int gn = n0 + wn + ni * 16 + l16;      // virtual col; region uniform per ni
    const float bvn = bias[wn + ni * 16 + l16];
    if (gn < 1024) {                             // Q plain, pre-scaled
      u16* base = Qd + gn;
#pragma unroll
      for (int mi = 0; mi < 4; ++mi)
#pragma unroll
        for (int r = 0; r < 4; ++r)
          base[(size_t)(gmb + mi * 16 + r) * 1024] = f2bf((acc[mi][ni][r] + bvn) * QSCALE);
    } else if (gn < 2048) {                      // K plain
      u16* base = Kd + (gn - 1024);
#pragma unroll
      for (int mi = 0; mi < 4; ++mi)
#pragma unroll
        for (int r = 0; r < 4; ++r)
          base[(size_t)(gmb + mi * 16 + r) * 1024] = f2bf(acc[mi][ni][r] + bvn);
    } else {                                     // V^T: [bh][dh][skv], packed x4
      const int col = gn - 2048, hh = col >> 6, dh = col & 63;
      u16* base = Vd + ((size_t)(bb * 16 + hh) * 64 + dh) * 2048 + ssb;
#pragma unroll
      for (int mi = 0; mi < 4; ++mi) {
        ushort4 o;
        o.x = f2bf(acc[mi][ni][0] + bvn);
        o.y = f2bf(acc[mi][ni][1] + bvn);
        o.z = f2bf(acc[mi][ni][2] + bvn);
        o.w = f2bf(acc[mi][ni][3] + bvn);
        *(ushort4*)(base + mi * 16) = o;
      }
    }
  }
}

// ---------------------------------------------------------------- flash attention
// R9 (R8 post-mortem: launch_bounds(1024,4) VGPR cap 128 vs ~190 live set ->
// spill, WRITE_SIZE 922 MB, 7x regression). Same TLP target (4 waves/SIMD)
// with HALF the per-wave state: 32 q-rows/wave (oacc 64->32 regs, qf 32->16,
// nominal live ~110 < 128 cap -> no spill). Block = 512 thr = 8 waves =
// 4 q-waves (BQ=128) x 2-way kv split; grid 512 = 2 blocks/CU -> 16 waves/CU.
// LDS 64 KB K/V pool + 1.5 KB lsum <= 80 KB so 2 blocks co-reside. O-merge
// reuses the K/V pool post-loop (grp 1 publishes 32 KB, grp 0 merges).
// Per-tile LDS frag traffic doubles vs R7 (~17 us of LDS pipe, not binding).
// K/V HBM refetch 2x but L2-resident per XCD (bid&31 = hb fixes XCD slice).
__global__ __launch_bounds__(512, 4) void flash_attn(
    const u16* __restrict__ Q, const u16* __restrict__ K,
    const u16* __restrict__ V, u16* __restrict__ O) {
  __shared__ uint4 sbuf[4096];              // 64 KB: [g*1024] K dbuf, +2048 V dbuf
  __shared__ float sLB[128];                // grp-1 lsum partials (per q row)
  __shared__ float sLA[128];                // 1/ltot (grp-0 wave-private)

  const int tid = threadIdx.x;
  const int wv = tid >> 6, lane = tid & 63;
  const int grp = wv >> 2, wq = wv & 3;     // kv-parity group, q-subblock owner
  const int c = lane & 31, hh = lane >> 5;  // col-in-block, half
  const int hb = blockIdx.x & 31;           // fast dim: (h, b) -> fixes XCD
  const int q0 = (blockIdx.x >> 5) * 128;   // slow dim: q-block (BQ=128)
  const int h = hb & 15, bz = hb >> 4;

  // Q,K plain [B*S][1024]; V^T [bh][dh][skv]. grp offset = 64 kv rows/cols.
  const u16* Qb = Q + ((size_t)(bz * 2048 + q0 + wq * 32)) * 1024 + h * 64;
  const u16* Kb = K + ((size_t)(bz * 2048 + grp * 64)) * 1024 + h * 64;
  const u16* Vb = V + ((size_t)(bz * 16 + h)) * 64 * 2048 + grp * 64;

  uint4* sKg = sbuf + grp * 1024;           // this group's K dbuf (2 x 512)
  uint4* sVg = sbuf + 2048 + grp * 1024;    // this group's V dbuf (2 x 512)

  // staging: slot i -> row i>>3, LDS chunk i&7 holds global chunk (i&7)^(row&7)
  const int i0 = wq * 128 + lane, i1 = i0 + 64;
  const int r0 = i0 >> 3, r1 = i1 >> 3;
  const int ck0 = (i0 & 7) ^ (r0 & 7), ck1 = (i1 & 7) ^ (r1 & 7);
  const u16* gK0 = Kb + (size_t)r0 * 1024 + ck0 * 8;
  const u16* gK1 = Kb + (size_t)r1 * 1024 + ck1 * 8;
  const u16* gV0 = Vb + (size_t)r0 * 2048 + ck0 * 8;
  const u16* gV1 = Vb + (size_t)r1 * 2048 + ck1 * 8;
  const int wo = wq * 128;

  // Q B-frags [s]: B[n=q][k=d], n = c, k = hh*8 + 16s + j   (32 q rows/wave)
  bf16x8 qf[4];
  {
    const u16* qr = Qb + (size_t)c * 1024 + hh * 8;
#pragma unroll
    for (int s = 0; s < 4; ++s)
      qf[s] = as_bf16x8(*(const uint4*)(qr + 16 * s));
  }

  f32x16 oacc[2] = {};                      // [nb]: O[qr][32nb+c]
  float lp = 0.f;                           // lsum partial (this half)

  // prologue: this group's tile 0 (global tile = grp) -> dbuf 0
  async16(gK0, sKg + wo);
  async16(gK1, sKg + wo + 64);
  async16(gV0, sVg + wo);
  async16(gV1, sVg + wo + 64);

  for (int t = 0; t < 16; ++t) {            // my tile = 2t + grp
    const int cur = t & 1;
    __syncthreads();   // drains my staging issued one iter ago
    if (t < 15) {
      const size_t ko = (size_t)(t + 1) * 128 * 1024;  // +2 tiles = 128 K rows
      const int vo = (t + 1) * 128;                    // 128 kv cols
      async16(gK0 + ko, sKg + (cur ^ 1) * 512 + wo);
      async16(gK1 + ko, sKg + (cur ^ 1) * 512 + wo + 64);
      async16(gV0 + vo, sVg + (cur ^ 1) * 512 + wo);
      async16(gV1 + vo, sVg + (cur ^ 1) * 512 + wo + 64);
    }
    const uint4* K_ = sKg + cur * 512;
    const uint4* V_ = sVg + cur * 512;

    // K A-frags [b][s]: A[m=kv=32b+c][k=d], chunk (2s+hh)^(row&7)
    bf16x8 kf[2][4];
#pragma unroll
    for (int b = 0; b < 2; ++b) {
      const int row = 32 * b + c, sw = row & 7;
#pragma unroll
      for (int s = 0; s < 4; ++s)
        kf[b][s] = as_bf16x8(K_[row * 8 + ((2 * s + hh) ^ sw)]);
    }

    // S^T per b -> exp2 -> in-register pack to PV A-frags pa[2b+sig]
    bf16x8 pa[4];
#pragma unroll
    for (int b = 0; b < 2; ++b) {
      f32x16 sAcc = {};
      __builtin_amdgcn_s_setprio(1);
#pragma unroll
      for (int s = 0; s < 4; ++s)
        sAcc = __builtin_amdgcn_mfma_f32_32x32x16_bf16(kf[b][s], qf[s], sAcc, 0, 0, 0);
      __builtin_amdgcn_s_setprio(0);
      // lane holds S[q=c][kv32 = (r&3)+8*(r>>2)+4*hh] for this 32-kv block
      float e[16];
#pragma unroll
      for (int r = 0; r < 16; ++r) e[r] = __builtin_amdgcn_exp2f(sAcc[r]);
      float t0 = (e[0] + e[1]) + (e[2] + e[3]);
      float t1 = (e[4] + e[5]) + (e[6] + e[7]);
      float t2 = (e[8] + e[9]) + (e[10] + e[11]);
      float t3 = (e[12] + e[13]) + (e[14] + e[15]);
      lp += (t0 + t1) + (t2 + t3);
      // pack pairs (kv even, odd) then cross-half swap: frag sig=0 covers
      // kv 0..15 of this block (k = 8*hh + j), sig=1 covers kv 16..31.
      u32 wA0 = pkbf(e[0], e[1]),   wA1 = pkbf(e[2], e[3]);
      u32 wB0 = pkbf(e[4], e[5]),   wB1 = pkbf(e[6], e[7]);
      u32 wC0 = pkbf(e[8], e[9]),   wC1 = pkbf(e[10], e[11]);
      u32 wD0 = pkbf(e[12], e[13]), wD1 = pkbf(e[14], e[15]);
      asm("v_permlane32_swap_b32 %0, %1" : "+v"(wA0), "+v"(wB0));
      asm("v_permlane32_swap_b32 %0, %1" : "+v"(wA1), "+v"(wB1));
      asm("v_permlane32_swap_b32 %0, %1" : "+v"(wC0), "+v"(wD0));
      asm("v_permlane32_swap_b32 %0, %1" : "+v"(wC1), "+v"(wD1));
      uint4 f0 = {wA0, wA1, wB0, wB1};
      uint4 f1 = {wC0, wC1, wD0, wD1};
      pa[2 * b]     = as_bf16x8(f0);
      pa[2 * b + 1] = as_bf16x8(f1);
    }

    // V B-frags [nb][ks]: B[k=kv][n=dh=32nb+c], chunk (2ks+hh)^(row&7)
    bf16x8 vf[2][4];
#pragma unroll
    for (int nb = 0; nb < 2; ++nb) {
      const int row = 32 * nb + c, sw = row & 7;
#pragma unroll
      for (int ks = 0; ks < 4; ++ks)
        vf[nb][ks] = as_bf16x8(V_[row * 8 + ((2 * ks + hh) ^ sw)]);
    }

    // PV: O[q][dh] += P * V
    __builtin_amdgcn_s_setprio(1);
#pragma unroll
    for (int nb = 0; nb < 2; ++nb)
#pragma unroll
      for (int ks = 0; ks < 4; ++ks)
        oacc[nb] = __builtin_amdgcn_mfma_f32_32x32x16_bf16(
            pa[ks], vf[nb][ks], oacc[nb], 0, 0, 0);
    __builtin_amdgcn_s_setprio(0);
  }

  // lsum: combine the two 32-kv halves within this wave
  float rtot;
  {
    u32 a = __builtin_bit_cast(u32, lp);
    u32 b = a;
    asm("v_permlane32_swap_b32 %0, %1" : "+v"(a), "+v"(b));
    rtot = __builtin_bit_cast(float, a) + __builtin_bit_cast(float, b);
  }
  if (grp) sLB[wq * 32 + c] = rtot;         // both halves write same value

  __syncthreads();   // (A) last-tile reads done -> sbuf reusable; sLB visible
  float* scr = (float*)sbuf;                // 16384 f32 scratch

  if (grp) {
    // publish odd-tile partial O (4 waves x 8 KB = 32 KB, lane-major)
#pragma unroll
    for (int nb = 0; nb < 2; ++nb) {
      float* dst = scr + (wq * 2 + nb) * 1024;
#pragma unroll
      for (int r = 0; r < 16; ++r)
        dst[r * 64 + lane] = oacc[nb][r];
    }
  }
  __syncthreads();   // (B)
  if (!grp) {
    // merge, invert lsum (sLA wave-private: lgkm ordering suffices), store O
#pragma unroll
    for (int nb = 0; nb < 2; ++nb) {
      const float* sp = scr + (wq * 2 + nb) * 1024;
#pragma unroll
      for (int r = 0; r < 16; ++r)
        oacc[nb][r] += sp[r * 64 + lane];
    }
    float tot = rtot + sLB[wq * 32 + c];
    sLA[wq * 32 + c] = 1.0f / tot;

    u16* Ob = O + ((size_t)(bz * 2048 + q0 + wq * 32)) * 1024 + h * 64;
#pragma unroll
    for (int nb = 0; nb < 2; ++nb)
#pragma unroll
      for (int r = 0; r < 16; ++r) {
        const int qr = (r & 3) + 8 * (r >> 2) + 4 * hh;
        float rl = sLA[wq * 32 + qr];        // broadcast read
        Ob[(size_t)qr * 1024 + nb * 32 + c] = f2bf(oacc[nb][r] * rl);
      }
  }
}

// ---------------------------------------------------------------- output projection
__global__ __launch_bounds__(256, 2) void gemm_out(
    const u16* __restrict__ A, const u16* __restrict__ Bt,
    const float* __restrict__ bias, float* __restrict__ C) {
  __shared__ uint4 sA[256], sB[512];
  f32x4 acc[2][4] = {};
  const int n0 = blockIdx.x * 128, m0 = blockIdx.y * 64;
  gemm_core<2>(A, Bt + (size_t)n0 * 1024, m0, sA, sB, acc);

  const int tid = threadIdx.x, wv = tid >> 6, lane = tid & 63;
  const int quad = lane >> 4, l16 = lane & 15;
  const int wm = (wv >> 1) * 32, wn = (wv & 1) * 64;
  float bv[4];
#pragma unroll
  for (int ni = 0; ni < 4; ++ni) bv[ni] = bias[n0 + wn + ni * 16 + l16];
#pragma unroll
  for (int mi = 0; mi < 2; ++mi)
#pragma unroll
    for (int ni = 0; ni < 4; ++ni)
#pragma unroll
      for (int r = 0; r < 4; ++r) {
        int gm = m0 + wm + mi * 16 + quad * 4 + r;
        int gn = n0 + wn + ni * 16 + l16;
        C[(size_t)gm * 1024 + gn] = acc[mi][ni][r] + bv[ni];
      }
}

extern "C" void kernel_launch(void* const* d_in, const int* in_sizes, int n_in,
                              void* d_out, int out_size, void* d_ws, size_t ws_size,
                              hipStream_t stream) {
  const float* xq  = (const float*)d_in[0];
  const float* xkv = (const float*)d_in[1];
  const float* Wq  = (const float*)d_in[2];
  const float* bq  = (const float*)d_in[3];
  const float* Wkv = (const float*)d_in[4];
  const float* bkv = (const float*)d_in[5];
  const float* Wo  = (const float*)d_in[6];
  const float* bo  = (const float*)d_in[7];
  float* out = (float*)d_out;

  char* p = (char*)d_ws;                       // 56 MiB total
  u16* Xq16  = (u16*)p; p += (size_t)8 << 20;  // [4096][1024] bf16
  u16* Xkv16 = (u16*)p; p += (size_t)8 << 20;
  u16* WqT   = (u16*)p; p += (size_t)2 << 20;  // [1024][1024]
  u16* WkvT  = (u16*)p; p += (size_t)4 << 20;  // [2048][1024]
  u16* WoT   = (u16*)p; p += (size_t)2 << 20;
  u16* Q16   = (u16*)p; p += (size_t)8 << 20;  // plain [4096][1024], pre-scaled
  u16* K16   = (u16*)p; p += (size_t)8 << 20;  // plain [4096][1024]
  u16* Vt16  = (u16*)p; p += (size_t)8 << 20;  // [bh][dh][skv]
  u16* O16   = (u16*)p; p += (size_t)8 << 20;  // plain [4096][1024]

  prep_kernel<<<14336, 256, 0, stream>>>(xq, xkv, Wq, Wkv, Wo,
                                         Xq16, Xkv16, WqT, WkvT, WoT);
  gemm_qkv<<<dim3(24, 32), 256, 0, stream>>>(Xq16, Xkv16, WqT, WkvT, bq, bkv,
                                             Q16, K16, Vt16);
  flash_attn<<<512, 512, 0, stream>>>(Q16, K16, Vt16, O16);
  gemm_out<<<dim3(8, 64), 256, 0, stream>>>(O16, WoT, bo, out);
}